// Round 15
// baseline (65.176 us; speedup 1.0000x reference)
//
#include <hip/hip_runtime.h>
#include <stdint.h>

typedef uint64_t u64;
typedef uint32_t u32;
typedef float v2f __attribute__((ext_vector_type(2)));   /* -> VOP3P v_pk_* */

#define NB    8
#define NQ    4096
#define NKEY  4096
#define CV    64
#define KSEL  16
#define G     4              /* queries per wave */
#define NWAVE 2              /* waves per block */
#define BLK   (NWAVE * 64)   /* 128 threads */
#define QPB   (G * NWAVE)    /* 8 queries per block */
#define CMAX  64             /* logical candidate limit per query */
#define CPAD  80             /* padded row: unguarded append, clamped addr */
#define PADU  (~(u64)0)

__device__ __forceinline__ u64 shflxor_u64(u64 v, int m) {
    const u32 lo = __shfl_xor((int)(u32)v, m);
    const u32 hi = __shfl_xor((int)(u32)(v >> 32), m);
    return (((u64)hi) << 32) | lo;
}
__device__ __forceinline__ int mbcnt64(u64 m) {
    return (int)__builtin_amdgcn_mbcnt_hi((u32)(m >> 32),
               __builtin_amdgcn_mbcnt_lo((u32)m, 0));
}
/* monotone float -> u32 key (metric k2-2q.k can be negative) */
__device__ __forceinline__ u32 fkey(float f) {
    const u32 b = __float_as_uint(f);
    return b ^ (0x80000000u | (u32)((int32_t)b >> 31));
}
__device__ __forceinline__ void ce64(u64& v, u64 p, bool keepmin) {
    const u64 mn = v < p ? v : p, mx = v < p ? p : v;
    v = keepmin ? mn : mx;
}

/* 2-way interleaved EXACT smallest-16-of-64 selection network (R13-proven) */
__device__ __forceinline__ void top16of64x2(u64& a, u64& b, int lane) {
#pragma unroll
    for (int k = 2; k <= 16; k <<= 1) {
#pragma unroll
        for (int j = k >> 1; j > 0; j >>= 1) {
            const bool keepmin = (((lane & j) == 0) == ((lane & k) == 0));
            const u64 pa = shflxor_u64(a, j);
            const u64 pb = shflxor_u64(b, j);
            ce64(a, pa, keepmin); ce64(b, pb, keepmin);
        }
    }
    {   const bool keepmin = ((lane & 16) == 0);
        const u64 pa = shflxor_u64(a, 16);
        const u64 pb = shflxor_u64(b, 16);
        ce64(a, pa, keepmin); ce64(b, pb, keepmin); }
#pragma unroll
    for (int j = 8; j > 0; j >>= 1) {
        const bool keepmin = (((lane & j) == 0) == ((lane & 32) == 0));
        const u64 pa = shflxor_u64(a, j);
        const u64 pb = shflxor_u64(b, j);
        ce64(a, pa, keepmin); ce64(b, pb, keepmin);
    }
    {   const bool keepmin = ((lane & 32) == 0);
        const u64 pa = shflxor_u64(a, 32);
        const u64 pb = shflxor_u64(b, 32);
        ce64(a, pa, keepmin); ce64(b, pb, keepmin); }
}

/* cold overflow fallback (~never; one code copy, uniform branch) */
__device__ __noinline__ int exact_recollect(const float4* __restrict__ kp4,
                                            int lane, float m2xq, float m2yq,
                                            u64* __restrict__ row) {
    u32 lo = 0, hi = ~0u;
#pragma unroll 1
    while (lo < hi) {
        const u32 mid = lo + ((hi - lo) >> 1);
        int cc = 0;
#pragma unroll 1
        for (int c = 0; c < 32; ++c) {
            const float4 kk = kp4[c * 64 + lane];
            const float k2a = fmaf(kk.x, kk.x, kk.y * kk.y);
            const float k2b = fmaf(kk.z, kk.z, kk.w * kk.w);
            const float va = fmaf(kk.x, m2xq, fmaf(kk.y, m2yq, k2a));
            const float vb = fmaf(kk.z, m2xq, fmaf(kk.w, m2yq, k2b));
            cc += (fkey(va) <= mid) ? 1 : 0;
            cc += (fkey(vb) <= mid) ? 1 : 0;
        }
#pragma unroll 1
        for (int off = 32; off; off >>= 1) cc += __shfl_xor(cc, off);
        if (cc >= KSEL) hi = mid; else lo = mid + 1;
    }
    int cc = 0;
#pragma unroll 1
    for (int c = 0; c < 32; ++c) {
        const float4 kk = kp4[c * 64 + lane];
        const float k2a = fmaf(kk.x, kk.x, kk.y * kk.y);
        const float k2b = fmaf(kk.z, kk.z, kk.w * kk.w);
        const float va = fmaf(kk.x, m2xq, fmaf(kk.y, m2yq, k2a));
        const float vb = fmaf(kk.z, m2xq, fmaf(kk.w, m2yq, k2b));
        const u32 ta = fkey(va), tb = fkey(vb);
        const bool aa = ta <= lo, ab = tb <= lo;
        const u64 mka = __ballot(aa);
        const u64 mkb = __ballot(ab);
        const int posa = cc + mbcnt64(mka);
        cc += (int)__popcll(mka);
        const int posb = cc + mbcnt64(mkb);
        cc += (int)__popcll(mkb);
        const u32 ia = (u32)(2 * (c * 64 + lane));
        if (aa && posa < CMAX) row[posa] = (((u64)ta) << 32) | ia;
        if (ab && posb < CMAX) row[posb] = (((u64)tb) << 32) | (ia + 1);
    }
    return cc < CMAX ? cc : CMAX;
}

/* setup: 9 query-independent affine sums over H=64 -> d_ws */
__global__ void setup_kernel(const float* __restrict__ qw, const float* __restrict__ qb,
                             const float* __restrict__ kw, const float* __restrict__ kb,
                             float* __restrict__ w9)
{
    const int h = threadIdx.x & 63;
    const float2 a = ((const float2*)qw)[h];
    const float2 c = ((const float2*)kw)[h];
    const float qbh = qb[h], kbh = kb[h];
    float s[9] = { a.x * c.x, a.y * c.x, qbh * c.x,
                   a.x * c.y, a.y * c.y, qbh * c.y,
                   a.x * kbh, a.y * kbh, qbh * kbh };
#pragma unroll
    for (int i = 0; i < 9; ++i)
#pragma unroll
        for (int off = 32; off; off >>= 1) s[i] += __shfl_xor(s[i], off);
    if (h == 0) {
#pragma unroll
        for (int i = 0; i < 9; ++i) w9[i] = s[i];
    }
}

extern "C" __global__ __launch_bounds__(BLK, 6) void bev_main(
    const float* __restrict__ qg, const float* __restrict__ kg,
    const float* __restrict__ vg, const float* __restrict__ w9,
    float* __restrict__ outg)
{
    __shared__ u64 cand[NWAVE][G][CPAD];      /* 5 KB; per-wave private */

    const int tid  = threadIdx.x;
    const int wv   = tid >> 6;
    const int lane = tid & 63;
    const int wvu  = __builtin_amdgcn_readfirstlane(wv);
    const int b    = blockIdx.x >> 9;                  /* 512 blocks per batch */
    const int qbase = ((int)(blockIdx.x & 511) * NWAVE + wvu) * G;

    const float2* kp  = (const float2*)(kg + (size_t)b * NKEY * 2);
    const float4* kp4 = (const float4*)kp;             /* 2 keys / 16 B */
    const float2* qp  = (const float2*)qg + (size_t)b * NQ + qbase;

    float m2x[G], m2y[G];
#pragma unroll
    for (int q = 0; q < G; ++q) {
        const float2 qc = qp[q];
        m2x[q] = -2.f * qc.x; m2y[q] = -2.f * qc.y;
    }

    /* ---- pass 1: per-lane metric-min per query, packed-f32 metric ---- */
    float mn[G];
#pragma unroll
    for (int q = 0; q < G; ++q) mn[q] = __builtin_inff();
#pragma unroll 8
    for (int c = 0; c < 32; ++c) {
        const float4 kk = kp4[c * 64 + lane];
        v2f kx, ky;                                    /* (key a, key b) packed */
        kx.x = kk.x; kx.y = kk.z;
        ky.x = kk.y; ky.y = kk.w;
        const v2f k2 = kx * kx + ky * ky;              /* v_pk_mul + v_pk_fma */
#pragma unroll
        for (int q = 0; q < G; ++q) {
            const v2f met = kx * m2x[q] + (ky * m2y[q] + k2);  /* 2x v_pk_fma */
            mn[q] = fminf(fminf(met.x, met.y), mn[q]); /* min3-fusable */
        }
    }

    /* ---- thresholds: 16th-smallest of 64 lane-mins (4-way interleaved) ---- */
    float thr[G];
    {
        float v0 = mn[0], v1 = mn[1], v2 = mn[2], v3 = mn[3];
#pragma unroll
        for (int k = 2; k <= 64; k <<= 1) {
#pragma unroll
            for (int j = k >> 1; j > 0; j >>= 1) {
                const bool keepmin = (((lane & j) == 0) == ((lane & k) == 0));
                const float p0 = __shfl_xor(v0, j);
                const float p1 = __shfl_xor(v1, j);
                const float p2 = __shfl_xor(v2, j);
                const float p3 = __shfl_xor(v3, j);
                v0 = keepmin ? fminf(v0, p0) : fmaxf(v0, p0);
                v1 = keepmin ? fminf(v1, p1) : fmaxf(v1, p1);
                v2 = keepmin ? fminf(v2, p2) : fmaxf(v2, p2);
                v3 = keepmin ? fminf(v3, p3) : fmaxf(v3, p3);
            }
        }
        thr[0] = __shfl(v0, 15); thr[1] = __shfl(v1, 15);
        thr[2] = __shfl(v2, 15); thr[3] = __shfl(v3, 15);
    }

    /* ---- pass 2: packed metric, unguarded ballot-append (clamped addr) ---- */
    int cnt[G];
#pragma unroll
    for (int q = 0; q < G; ++q) cnt[q] = 0;
#pragma unroll 4
    for (int c = 0; c < 32; ++c) {
        const float4 kk = kp4[c * 64 + lane];
        v2f kx, ky;
        kx.x = kk.x; kx.y = kk.z;
        ky.x = kk.y; ky.y = kk.w;
        const v2f k2 = kx * kx + ky * ky;
        const u32 ia = (u32)(2 * (c * 64 + lane));
#pragma unroll
        for (int q = 0; q < G; ++q) {
            const v2f met = kx * m2x[q] + (ky * m2y[q] + k2);
            const bool aa = met.x <= thr[q];
            const bool ab = met.y <= thr[q];
            const u64 mka = __ballot(aa);
            const u64 mkb = __ballot(ab);
            if (mka | mkb) {                           /* uniform branch */
                const int posa = cnt[q] + mbcnt64(mka);
                cnt[q] += (int)__popcll(mka);
                const int posb = cnt[q] + mbcnt64(mkb);
                cnt[q] += (int)__popcll(mkb);
                if (aa)
                    cand[wv][q][posa < CPAD - 1 ? posa : CPAD - 1] =
                        (((u64)fkey(met.x)) << 32) | ia;
                if (ab)
                    cand[wv][q][posb < CPAD - 1 ? posb : CPAD - 1] =
                        (((u64)fkey(met.y)) << 32) | (ia + 1);
            }
        }
    }

    /* ---- overflow fallback (~never; overwrite clobbered row exactly) ---- */
#pragma unroll
    for (int q = 0; q < G; ++q) {
        if (cnt[q] > CMAX) {
            const float2 qc = qp[q];
            cnt[q] = exact_recollect(kp4, lane, -2.f * qc.x, -2.f * qc.y,
                                     &cand[wv][q][0]);
        }
    }

    /* ---- epilogue: query pairs, fully unrolled, chains interleaved ---- */
    const float s1 = w9[0], s2 = w9[1], s3 = w9[2];
    const float s4 = w9[3], s5 = w9[4], s6 = w9[5];
    const float s7 = w9[6], s8 = w9[7], s9 = w9[8];
    const float* vb = vg + (size_t)b * NKEY * CV;

#pragma unroll
    for (int pr = 0; pr < G / 2; ++pr) {
        const int qa = 2 * pr, qb2 = 2 * pr + 1;

        u64 mya = (lane < cnt[qa])  ? cand[wv][qa][lane]  : PADU;
        u64 myb = (lane < cnt[qb2]) ? cand[wv][qb2][lane] : PADU;
        top16of64x2(mya, myb, lane);
        const u32 idxa = (u32)mya, idxb = (u32)myb;

        const float2 qca = qp[qa], qcb = qp[qb2];
        const float Aa  = fmaf(qca.x, s1, fmaf(qca.y, s2, s3));
        const float Ba  = fmaf(qca.x, s4, fmaf(qca.y, s5, s6));
        const float Ca  = fmaf(qca.x, s7, fmaf(qca.y, s8, s9));
        const float Ab  = fmaf(qcb.x, s1, fmaf(qcb.y, s2, s3));
        const float Bbb = fmaf(qcb.x, s4, fmaf(qcb.y, s5, s6));
        const float Cb  = fmaf(qcb.x, s7, fmaf(qcb.y, s8, s9));

        const int sela = (lane < KSEL) ? (int)idxa : 0;
        const int selb = (lane < KSEL) ? (int)idxb : 0;
        const float2 kca = kp[sela];
        const float2 kcb = kp[selb];
        const float sca = fmaf(Aa, kca.x, fmaf(Ba,  kca.y, Ca));
        const float scb = fmaf(Ab, kcb.x, fmaf(Bbb, kcb.y, Cb));

        float mxa = sca, mxb = scb;
#pragma unroll
        for (int off = 8; off; off >>= 1) {
            mxa = fmaxf(mxa, __shfl_xor(mxa, off));
            mxb = fmaxf(mxb, __shfl_xor(mxb, off));
        }
        const float ea = __expf(sca - mxa);
        const float eb = __expf(scb - mxb);
        float sua = ea, sub = eb;
#pragma unroll
        for (int off = 8; off; off >>= 1) {
            sua += __shfl_xor(sua, off);
            sub += __shfl_xor(sub, off);
        }
        const float wa = ea / sua;                    /* valid lanes 0..15 */
        const float wb = eb / sub;

        float acca = 0.f, accb = 0.f;
#pragma unroll
        for (int s = 0; s < KSEL; ++s) {
            const u32 ida = (u32)__builtin_amdgcn_readlane((int)idxa, s);
            const u32 idb = (u32)__builtin_amdgcn_readlane((int)idxb, s);
            const float wsa = __uint_as_float(
                (u32)__builtin_amdgcn_readlane((int)__float_as_uint(wa), s));
            const float wsb = __uint_as_float(
                (u32)__builtin_amdgcn_readlane((int)__float_as_uint(wb), s));
            acca = fmaf(wsa, vb[(size_t)ida * CV + lane], acca);
            accb = fmaf(wsb, vb[(size_t)idb * CV + lane], accb);
        }
        outg[((size_t)b * NQ + qbase + qa)  * CV + lane] = acca;
        outg[((size_t)b * NQ + qbase + qb2) * CV + lane] = accb;
    }
}

extern "C" void kernel_launch(void* const* d_in, const int* in_sizes, int n_in,
                              void* d_out, int out_size, void* d_ws, size_t ws_size,
                              hipStream_t stream) {
    const float* q  = (const float*)d_in[0];
    const float* k  = (const float*)d_in[1];
    const float* v  = (const float*)d_in[2];
    const float* qw = (const float*)d_in[3];
    const float* qb = (const float*)d_in[4];
    const float* kw = (const float*)d_in[5];
    const float* kb = (const float*)d_in[6];
    /* d_in[7] = top_k (always 16; compile-time) */
    float* out = (float*)d_out;
    float* w9  = (float*)d_ws;

    hipLaunchKernelGGL(setup_kernel, dim3(1), dim3(64), 0, stream,
                       qw, qb, kw, kb, w9);
    hipLaunchKernelGGL(bev_main, dim3(NB * NQ / QPB), dim3(BLK),
                       0, stream, q, k, v, w9, out);
}

// Round 16
// 63.724 us; speedup vs baseline: 1.0228x; 1.0228x over previous
//
#include <hip/hip_runtime.h>
#include <stdint.h>

typedef uint64_t u64;
typedef uint32_t u32;

#define NB    8
#define NQ    4096
#define NKEY  4096
#define CV    64
#define KSEL  16
#define G     4              /* queries per wave */
#define NWAVE 2              /* waves per block */
#define BLK   (NWAVE * 64)   /* 128 threads */
#define QPB   (G * NWAVE)    /* 8 queries per block */
#define CMAX  64             /* logical candidate limit per query */
#define CPAD  80             /* padded row: unguarded append, clamped addr */
#define PADU  (~(u64)0)

__device__ __forceinline__ u64 shflxor_u64(u64 v, int m) {
    const u32 lo = __shfl_xor((int)(u32)v, m);
    const u32 hi = __shfl_xor((int)(u32)(v >> 32), m);
    return (((u64)hi) << 32) | lo;
}
__device__ __forceinline__ int mbcnt64(u64 m) {
    return (int)__builtin_amdgcn_mbcnt_hi((u32)(m >> 32),
               __builtin_amdgcn_mbcnt_lo((u32)m, 0));
}
/* monotone float -> u32 key (metric k2-2q.k can be negative) */
__device__ __forceinline__ u32 fkey(float f) {
    const u32 b = __float_as_uint(f);
    return b ^ (0x80000000u | (u32)((int32_t)b >> 31));
}
__device__ __forceinline__ void ce64(u64& v, u64 p, bool keepmin) {
    const u64 mn = v < p ? v : p, mx = v < p ? p : v;
    v = keepmin ? mn : mx;
}

/* 2-way interleaved EXACT smallest-16-of-64 selection network (R13-proven) */
__device__ __forceinline__ void top16of64x2(u64& a, u64& b, int lane) {
#pragma unroll
    for (int k = 2; k <= 16; k <<= 1) {
#pragma unroll
        for (int j = k >> 1; j > 0; j >>= 1) {
            const bool keepmin = (((lane & j) == 0) == ((lane & k) == 0));
            const u64 pa = shflxor_u64(a, j);
            const u64 pb = shflxor_u64(b, j);
            ce64(a, pa, keepmin); ce64(b, pb, keepmin);
        }
    }
    {   const bool keepmin = ((lane & 16) == 0);
        const u64 pa = shflxor_u64(a, 16);
        const u64 pb = shflxor_u64(b, 16);
        ce64(a, pa, keepmin); ce64(b, pb, keepmin); }
#pragma unroll
    for (int j = 8; j > 0; j >>= 1) {
        const bool keepmin = (((lane & j) == 0) == ((lane & 32) == 0));
        const u64 pa = shflxor_u64(a, j);
        const u64 pb = shflxor_u64(b, j);
        ce64(a, pa, keepmin); ce64(b, pb, keepmin);
    }
    {   const bool keepmin = ((lane & 32) == 0);
        const u64 pa = shflxor_u64(a, 32);
        const u64 pb = shflxor_u64(b, 32);
        ce64(a, pa, keepmin); ce64(b, pb, keepmin); }
}

/* cold overflow fallback (~never; one code copy, uniform branch) */
__device__ __noinline__ int exact_recollect(const float4* __restrict__ kp4,
                                            int lane, float m2xq, float m2yq,
                                            u64* __restrict__ row) {
    u32 lo = 0, hi = ~0u;
#pragma unroll 1
    while (lo < hi) {
        const u32 mid = lo + ((hi - lo) >> 1);
        int cc = 0;
#pragma unroll 1
        for (int c = 0; c < 32; ++c) {
            const float4 kk = kp4[c * 64 + lane];
            const float k2a = fmaf(kk.x, kk.x, kk.y * kk.y);
            const float k2b = fmaf(kk.z, kk.z, kk.w * kk.w);
            const float va = fmaf(kk.x, m2xq, fmaf(kk.y, m2yq, k2a));
            const float vb = fmaf(kk.z, m2xq, fmaf(kk.w, m2yq, k2b));
            cc += (fkey(va) <= mid) ? 1 : 0;
            cc += (fkey(vb) <= mid) ? 1 : 0;
        }
#pragma unroll 1
        for (int off = 32; off; off >>= 1) cc += __shfl_xor(cc, off);
        if (cc >= KSEL) hi = mid; else lo = mid + 1;
    }
    int cc = 0;
#pragma unroll 1
    for (int c = 0; c < 32; ++c) {
        const float4 kk = kp4[c * 64 + lane];
        const float k2a = fmaf(kk.x, kk.x, kk.y * kk.y);
        const float k2b = fmaf(kk.z, kk.z, kk.w * kk.w);
        const float va = fmaf(kk.x, m2xq, fmaf(kk.y, m2yq, k2a));
        const float vb = fmaf(kk.z, m2xq, fmaf(kk.w, m2yq, k2b));
        const u32 ta = fkey(va), tb = fkey(vb);
        const bool aa = ta <= lo, ab = tb <= lo;
        const u64 mka = __ballot(aa);
        const u64 mkb = __ballot(ab);
        const int posa = cc + mbcnt64(mka);
        cc += (int)__popcll(mka);
        const int posb = cc + mbcnt64(mkb);
        cc += (int)__popcll(mkb);
        const u32 ia = (u32)(2 * (c * 64 + lane));
        if (aa && posa < CMAX) row[posa] = (((u64)ta) << 32) | ia;
        if (ab && posb < CMAX) row[posb] = (((u64)tb) << 32) | (ia + 1);
    }
    return cc < CMAX ? cc : CMAX;
}

/* setup: 9 query-independent affine sums over H=64 -> d_ws */
__global__ void setup_kernel(const float* __restrict__ qw, const float* __restrict__ qb,
                             const float* __restrict__ kw, const float* __restrict__ kb,
                             float* __restrict__ w9)
{
    const int h = threadIdx.x & 63;
    const float2 a = ((const float2*)qw)[h];
    const float2 c = ((const float2*)kw)[h];
    const float qbh = qb[h], kbh = kb[h];
    float s[9] = { a.x * c.x, a.y * c.x, qbh * c.x,
                   a.x * c.y, a.y * c.y, qbh * c.y,
                   a.x * kbh, a.y * kbh, qbh * kbh };
#pragma unroll
    for (int i = 0; i < 9; ++i)
#pragma unroll
        for (int off = 32; off; off >>= 1) s[i] += __shfl_xor(s[i], off);
    if (h == 0) {
#pragma unroll
        for (int i = 0; i < 9; ++i) w9[i] = s[i];
    }
}

extern "C" __global__ __launch_bounds__(BLK, 6) void bev_main(
    const float* __restrict__ qg, const float* __restrict__ kg,
    const float* __restrict__ vg, const float* __restrict__ w9,
    float* __restrict__ outg)
{
    __shared__ u64 cand[NWAVE][G][CPAD];      /* 5 KB; per-wave private */

    const int tid  = threadIdx.x;
    const int wv   = tid >> 6;
    const int lane = tid & 63;
    const int wvu  = __builtin_amdgcn_readfirstlane(wv);
    const int b    = blockIdx.x >> 9;                  /* 512 blocks per batch */
    const int qbase = ((int)(blockIdx.x & 511) * NWAVE + wvu) * G;

    const float2* kp  = (const float2*)(kg + (size_t)b * NKEY * 2);
    const float4* kp4 = (const float4*)kp;             /* 2 keys / 16 B */
    const float2* qp  = (const float2*)qg + (size_t)b * NQ + qbase;

    float m2x[G], m2y[G];
#pragma unroll
    for (int q = 0; q < G; ++q) {
        const float2 qc = qp[q];
        m2x[q] = -2.f * qc.x; m2y[q] = -2.f * qc.y;
    }

    /* ---- pass 1: per-lane metric-min per query (shared key loads) ---- */
    float mn[G];
#pragma unroll
    for (int q = 0; q < G; ++q) mn[q] = __builtin_inff();
#pragma unroll 8
    for (int c = 0; c < 32; ++c) {
        const float4 kk = kp4[c * 64 + lane];
        const float k2a = fmaf(kk.x, kk.x, kk.y * kk.y);
        const float k2b = fmaf(kk.z, kk.z, kk.w * kk.w);
#pragma unroll
        for (int q = 0; q < G; ++q) {
            const float va = fmaf(kk.x, m2x[q], fmaf(kk.y, m2y[q], k2a));
            const float vb = fmaf(kk.z, m2x[q], fmaf(kk.w, m2y[q], k2b));
            mn[q] = fminf(fminf(va, vb), mn[q]);       /* min3-fusable */
        }
    }

    /* ---- thresholds: 16th-smallest of 64 lane-mins (4-way interleaved) ---- */
    float thr[G];
    {
        float v0 = mn[0], v1 = mn[1], v2 = mn[2], v3 = mn[3];
#pragma unroll
        for (int k = 2; k <= 64; k <<= 1) {
#pragma unroll
            for (int j = k >> 1; j > 0; j >>= 1) {
                const bool keepmin = (((lane & j) == 0) == ((lane & k) == 0));
                const float p0 = __shfl_xor(v0, j);
                const float p1 = __shfl_xor(v1, j);
                const float p2 = __shfl_xor(v2, j);
                const float p3 = __shfl_xor(v3, j);
                v0 = keepmin ? fminf(v0, p0) : fmaxf(v0, p0);
                v1 = keepmin ? fminf(v1, p1) : fmaxf(v1, p1);
                v2 = keepmin ? fminf(v2, p2) : fmaxf(v2, p2);
                v3 = keepmin ? fminf(v3, p3) : fmaxf(v3, p3);
            }
        }
        thr[0] = __shfl(v0, 15); thr[1] = __shfl(v1, 15);
        thr[2] = __shfl(v2, 15); thr[3] = __shfl(v3, 15);
    }

    /* ---- pass 2: recompute metric, unguarded ballot-append (clamped addr) ---- */
    int cnt[G];
#pragma unroll
    for (int q = 0; q < G; ++q) cnt[q] = 0;
#pragma unroll 4
    for (int c = 0; c < 32; ++c) {
        const float4 kk = kp4[c * 64 + lane];
        const float k2a = fmaf(kk.x, kk.x, kk.y * kk.y);
        const float k2b = fmaf(kk.z, kk.z, kk.w * kk.w);
        const u32 ia = (u32)(2 * (c * 64 + lane));
#pragma unroll
        for (int q = 0; q < G; ++q) {
            const float va = fmaf(kk.x, m2x[q], fmaf(kk.y, m2y[q], k2a));
            const float vb = fmaf(kk.z, m2x[q], fmaf(kk.w, m2y[q], k2b));
            const bool aa = va <= thr[q];
            const bool ab = vb <= thr[q];
            const u64 mka = __ballot(aa);
            const u64 mkb = __ballot(ab);
            if (mka | mkb) {                           /* uniform branch */
                const int posa = cnt[q] + mbcnt64(mka);
                cnt[q] += (int)__popcll(mka);
                const int posb = cnt[q] + mbcnt64(mkb);
                cnt[q] += (int)__popcll(mkb);
                if (aa)
                    cand[wv][q][posa < CPAD - 1 ? posa : CPAD - 1] =
                        (((u64)fkey(va)) << 32) | ia;
                if (ab)
                    cand[wv][q][posb < CPAD - 1 ? posb : CPAD - 1] =
                        (((u64)fkey(vb)) << 32) | (ia + 1);
            }
        }
    }

    /* ---- overflow fallback (~never; overwrite clobbered row exactly) ---- */
#pragma unroll
    for (int q = 0; q < G; ++q) {
        if (cnt[q] > CMAX) {
            const float2 qc = qp[q];
            cnt[q] = exact_recollect(kp4, lane, -2.f * qc.x, -2.f * qc.y,
                                     &cand[wv][q][0]);
        }
    }

    /* ---- epilogue: query pairs, fully unrolled, chains interleaved ---- */
    const float s1 = w9[0], s2 = w9[1], s3 = w9[2];
    const float s4 = w9[3], s5 = w9[4], s6 = w9[5];
    const float s7 = w9[6], s8 = w9[7], s9 = w9[8];
    const float* vb = vg + (size_t)b * NKEY * CV;

#pragma unroll
    for (int pr = 0; pr < G / 2; ++pr) {
        const int qa = 2 * pr, qb2 = 2 * pr + 1;

        u64 mya = (lane < cnt[qa])  ? cand[wv][qa][lane]  : PADU;
        u64 myb = (lane < cnt[qb2]) ? cand[wv][qb2][lane] : PADU;
        top16of64x2(mya, myb, lane);
        const u32 idxa = (u32)mya, idxb = (u32)myb;

        const float2 qca = qp[qa], qcb = qp[qb2];
        const float Aa  = fmaf(qca.x, s1, fmaf(qca.y, s2, s3));
        const float Ba  = fmaf(qca.x, s4, fmaf(qca.y, s5, s6));
        const float Ca  = fmaf(qca.x, s7, fmaf(qca.y, s8, s9));
        const float Ab  = fmaf(qcb.x, s1, fmaf(qcb.y, s2, s3));
        const float Bbb = fmaf(qcb.x, s4, fmaf(qcb.y, s5, s6));
        const float Cb  = fmaf(qcb.x, s7, fmaf(qcb.y, s8, s9));

        const int sela = (lane < KSEL) ? (int)idxa : 0;
        const int selb = (lane < KSEL) ? (int)idxb : 0;
        const float2 kca = kp[sela];
        const float2 kcb = kp[selb];
        const float sca = fmaf(Aa, kca.x, fmaf(Ba,  kca.y, Ca));
        const float scb = fmaf(Ab, kcb.x, fmaf(Bbb, kcb.y, Cb));

        float mxa = sca, mxb = scb;
#pragma unroll
        for (int off = 8; off; off >>= 1) {
            mxa = fmaxf(mxa, __shfl_xor(mxa, off));
            mxb = fmaxf(mxb, __shfl_xor(mxb, off));
        }
        const float ea = __expf(sca - mxa);
        const float eb = __expf(scb - mxb);
        float sua = ea, sub = eb;
#pragma unroll
        for (int off = 8; off; off >>= 1) {
            sua += __shfl_xor(sua, off);
            sub += __shfl_xor(sub, off);
        }
        const float wa = ea / sua;                    /* valid lanes 0..15 */
        const float wb = eb / sub;

        float acca = 0.f, accb = 0.f;
#pragma unroll
        for (int s = 0; s < KSEL; ++s) {
            const u32 ida = (u32)__builtin_amdgcn_readlane((int)idxa, s);
            const u32 idb = (u32)__builtin_amdgcn_readlane((int)idxb, s);
            const float wsa = __uint_as_float(
                (u32)__builtin_amdgcn_readlane((int)__float_as_uint(wa), s));
            const float wsb = __uint_as_float(
                (u32)__builtin_amdgcn_readlane((int)__float_as_uint(wb), s));
            acca = fmaf(wsa, vb[(size_t)ida * CV + lane], acca);
            accb = fmaf(wsb, vb[(size_t)idb * CV + lane], accb);
        }
        outg[((size_t)b * NQ + qbase + qa)  * CV + lane] = acca;
        outg[((size_t)b * NQ + qbase + qb2) * CV + lane] = accb;
    }
}

extern "C" void kernel_launch(void* const* d_in, const int* in_sizes, int n_in,
                              void* d_out, int out_size, void* d_ws, size_t ws_size,
                              hipStream_t stream) {
    const float* q  = (const float*)d_in[0];
    const float* k  = (const float*)d_in[1];
    const float* v  = (const float*)d_in[2];
    const float* qw = (const float*)d_in[3];
    const float* qb = (const float*)d_in[4];
    const float* kw = (const float*)d_in[5];
    const float* kb = (const float*)d_in[6];
    /* d_in[7] = top_k (always 16; compile-time) */
    float* out = (float*)d_out;
    float* w9  = (float*)d_ws;

    hipLaunchKernelGGL(setup_kernel, dim3(1), dim3(64), 0, stream,
                       qw, qb, kw, kb, w9);
    hipLaunchKernelGGL(bev_main, dim3(NB * NQ / QPB), dim3(BLK),
                       0, stream, q, k, v, w9, out);
}